// Round 9
// baseline (3083.016 us; speedup 1.0000x reference)
//
#include <hip/hip_runtime.h>
#include <hip/hip_bf16.h>
#include <math.h>

// Problem constants
#define LSEQ 2048
#define DMODEL 1024
#define DINNER 2048
#define DSTATE 16
#define DCONV 4
#define DTRANK 64
#define RPROJ 96   // DTRANK + 2*DSTATE

// Chunked-scan decomposition
#define CHUNK 16
#define NCHUNK (LSEQ / CHUNK)   // 128

#define XSPLIT 4                // split-K factor for x_proj
#define TGRID 1024              // tail kernel grid (must be <= co-resident capacity)

typedef __attribute__((ext_vector_type(8))) short bf16x8;
typedef __attribute__((ext_vector_type(4))) float f32x4;

__device__ __forceinline__ float softplusf(float x) {
    return (x > 20.f) ? x : log1pf(__expf(x));
}
__device__ __forceinline__ float siluf(float x) {
    return x / (1.f + __expf(-x));
}
// f32 -> bf16 RTNE
__device__ __forceinline__ short f2bf(float f) {
    union { float f; unsigned u; } v; v.f = f;
    unsigned r = v.u + 0x7FFFu + ((v.u >> 16) & 1u);
    return (short)(r >> 16);
}
// bf16 -> f32
__device__ __forceinline__ float bf2f(short h) {
    union { unsigned u; float f; } v;
    v.u = ((unsigned)(unsigned short)h) << 16;
    return v.f;
}

__device__ __forceinline__ void cvt8(const float* __restrict__ s,
                                     short* __restrict__ d, int i) {
    const float4 a = *(const float4*)(s + i);
    const float4 b = *(const float4*)(s + i + 4);
    alignas(16) short h[8];
    h[0] = f2bf(a.x); h[1] = f2bf(a.y); h[2] = f2bf(a.z); h[3] = f2bf(a.w);
    h[4] = f2bf(b.x); h[5] = f2bf(b.y); h[6] = f2bf(b.z); h[7] = f2bf(b.w);
    *(uint4*)(d + i) = *(const uint4*)h;
}

// ---- grid-wide barrier: device-scope atomic counter + fences ----
// Counter must be pre-zeroed (done by cvt_weights, stream-ordered earlier).
__device__ __forceinline__ void gridbar(unsigned* cnt) {
    __syncthreads();
    __threadfence();                 // release: make this block's writes visible
    if (threadIdx.x == 0) {
        atomicAdd(cnt, 1u);
        while (__hip_atomic_load(cnt, __ATOMIC_ACQUIRE,
                                 __HIP_MEMORY_SCOPE_AGENT) < (unsigned)TGRID)
            __builtin_amdgcn_s_sleep(8);
    }
    __syncthreads();
    __threadfence();                 // acquire: invalidate stale L1 lines
}

// ---------------- fused f32 -> bf16 convert of all 4 weight tensors -------
// Also zeroes the 16 grid-barrier counters (d_ws is poisoned each launch).
__global__ __launch_bounds__(256) void cvt_weights(
    const float* __restrict__ s0, short* __restrict__ d0, int n0,
    const float* __restrict__ s1, short* __restrict__ d1, int n1,
    const float* __restrict__ s2, short* __restrict__ d2, int n2,
    const float* __restrict__ s3, short* __restrict__ d3, int n3,
    unsigned* __restrict__ bar)
{
    if (blockIdx.x == 0 && threadIdx.x < 16) bar[threadIdx.x] = 0u;
    int i = (blockIdx.x * 256 + threadIdx.x) * 8;
    if (i < n0) { cvt8(s0, d0, i); return; }
    i -= n0;
    if (i < n1) { cvt8(s1, d1, i); return; }
    i -= n1;
    if (i < n2) { cvt8(s2, d2, i); return; }
    i -= n2;
    if (i < n3) { cvt8(s3, d3, i); return; }
}

// ---------------- LayerNorm: one block per row; f32 or bf16 out ----------
__global__ __launch_bounds__(256) void ln_kernel(
    const float* __restrict__ x, const float* __restrict__ w,
    const float* __restrict__ b, float* __restrict__ outf,
    short* __restrict__ outb)
{
    __shared__ float s1[256], s2[256];
    const int row = blockIdx.x;
    const int tid = threadIdx.x;
    const float* xr = x + (size_t)row * DMODEL;
    float v[4];
    float s = 0.f, sq = 0.f;
#pragma unroll
    for (int k = 0; k < 4; k++) {
        v[k] = xr[k * 256 + tid];
        s += v[k];
        sq += v[k] * v[k];
    }
    s1[tid] = s; s2[tid] = sq;
    __syncthreads();
    for (int off = 128; off > 0; off >>= 1) {
        if (tid < off) { s1[tid] += s1[tid + off]; s2[tid] += s2[tid + off]; }
        __syncthreads();
    }
    const float mu = s1[0] * (1.f / DMODEL);
    const float var = s2[0] * (1.f / DMODEL) - mu * mu;
    const float rstd = rsqrtf(var + 1e-5f);
#pragma unroll
    for (int k = 0; k < 4; k++) {
        const int i = k * 256 + tid;
        const float o = (v[k] - mu) * rstd * w[i] + b[i];
        if (outf) outf[(size_t)row * DMODEL + i] = o;
        if (outb) outb[(size_t)row * DMODEL + i] = f2bf(o);
    }
}

// ------- bf16 MFMA NT GEMM, (32*MI) x (32*NJ) tile, double-buffered LDS ---
// (used for in_proj and x_proj; see tail_kernel for the fused rest)
// MODE 0: f32 store (csplit)   MODE 3: bf16 store
template<int MI, int NJ, int MODE>
__global__ __launch_bounds__(256) void gemm_mfma(
    const short* __restrict__ A, int lda,   // [M,lda] bf16
    const short* __restrict__ W, int ldw,   // [N,ldw] bf16
    float* __restrict__ Cf, short* __restrict__ Cb, int ldc,
    int M, int N, int K,
    size_t csplit)
{
    constexpr int BM = 32 * MI;
    constexpr int BN = 32 * NJ;
    constexpr int AISS = BM / 64;
    constexpr int WISS = BN / 64;
    __shared__ alignas(16) short As[2][BM * 32];
    __shared__ alignas(16) short Ws[2][BN * 32];

    const int tid = threadIdx.x;
    const int lane = tid & 63;
    const int w = tid >> 6;
    const int wr = w >> 1, wc = w & 1;
    const int row0 = blockIdx.y * BM;
    const int col0 = blockIdx.x * BN;
    const int kbeg = blockIdx.z * K;

    const int srow = tid >> 2;
    const int skch = ((tid & 3) ^ ((srow >> 1) & 3)) * 8;   // swizzled k chunk

    f32x4 acc[MI][NJ];
#pragma unroll
    for (int i = 0; i < MI; i++)
#pragma unroll
        for (int j = 0; j < NJ; j++) acc[i][j] = (f32x4)0.f;

    const int lrow = lane & 15;
    const int q = lane >> 4;
    const int NIT = K / 32;

    auto stage = [&](int p, int kt) {
#pragma unroll
        for (int j = 0; j < AISS; j++) {
            const short* gp = A + (size_t)(row0 + j * 64 + srow) * lda + kt + skch;
            __builtin_amdgcn_global_load_lds(
                (const __attribute__((address_space(1))) void*)gp,
                (__attribute__((address_space(3))) void*)(&As[p][j * 2048 + tid * 8]),
                16, 0, 0);
        }
#pragma unroll
        for (int j = 0; j < WISS; j++) {
            const int wrow = col0 + j * 64 + srow;
            if (wrow < N) {
                const short* gp = W + (size_t)wrow * ldw + kt + skch;
                __builtin_amdgcn_global_load_lds(
                    (const __attribute__((address_space(1))) void*)gp,
                    (__attribute__((address_space(3))) void*)(&Ws[p][j * 2048 + tid * 8]),
                    16, 0, 0);
            }
        }
    };

    stage(0, kbeg);
    __syncthreads();
    for (int it = 0; it < NIT; ++it) {
        const int p = it & 1;
        if (it + 1 < NIT) stage(p ^ 1, kbeg + (it + 1) * 32);

        bf16x8 af[MI], bfr[NJ];
#pragma unroll
        for (int i = 0; i < MI; i++) {
            const int R = wr * (16 * MI) + i * 16 + lrow;
            af[i] = *(const bf16x8*)&As[p][R * 32 + ((q ^ ((R >> 1) & 3)) * 8)];
        }
#pragma unroll
        for (int j = 0; j < NJ; j++) {
            const int R = wc * (16 * NJ) + j * 16 + lrow;
            bfr[j] = *(const bf16x8*)&Ws[p][R * 32 + ((q ^ ((R >> 1) & 3)) * 8)];
        }
#pragma unroll
        for (int i = 0; i < MI; i++)
#pragma unroll
            for (int j = 0; j < NJ; j++)
                acc[i][j] = __builtin_amdgcn_mfma_f32_16x16x32_bf16(
                    af[i], bfr[j], acc[i][j], 0, 0, 0);
        __syncthreads();
    }

    if (MODE == 0 && csplit) Cf += blockIdx.z * csplit;

    const int rbase = row0 + wr * (16 * MI);
    const int cbase = col0 + wc * (16 * NJ);
#pragma unroll
    for (int i = 0; i < MI; i++) {
#pragma unroll
        for (int j = 0; j < NJ; j++) {
            const int gcol = cbase + j * 16 + lrow;
            if (gcol < N) {
#pragma unroll
                for (int r = 0; r < 4; r++) {
                    const int grow = rbase + i * 16 + (lane >> 4) * 4 + r;
                    float v = acc[i][j][r];
                    if (MODE == 3) Cb[(size_t)grow * ldc + gcol] = f2bf(v);
                    else           Cf[(size_t)grow * ldc + gcol] = v;
                }
            }
        }
    }
}

// ---------------- Causal depthwise conv (k=4) + bias + silu --------------
__global__ __launch_bounds__(256) void conv_silu_kernel(
    const short* __restrict__ xzb, const float* __restrict__ cw,
    const float* __restrict__ cb, short* __restrict__ xcb)
{
    const int g = blockIdx.x * 256 + threadIdx.x;   // over L * DINNER/8
    const int t = g >> 8;
    const int c0 = (g & 255) * 8;
    float acc[8];
#pragma unroll
    for (int j = 0; j < 8; j++) acc[j] = cb[c0 + j];
#pragma unroll
    for (int k = 0; k < DCONV; k++) {
        const int tt = t - (DCONV - 1) + k;
        if (tt >= 0) {
            const bf16x8 v = *(const bf16x8*)(xzb + (size_t)tt * (2 * DINNER) + c0);
#pragma unroll
            for (int j = 0; j < 8; j++)
                acc[j] += bf2f(v[j]) * cw[(c0 + j) * DCONV + k];
        }
    }
    alignas(16) short h[8];
#pragma unroll
    for (int j = 0; j < 8; j++) h[j] = f2bf(siluf(acc[j]));
    *(uint4*)(xcb + (size_t)t * DINNER + c0) = *(const uint4*)h;
}

// ============ Fused layer tail: combine + dt_proj + scan(1,2,3) + out_proj
// One persistent kernel, TGRID=1024 blocks x 256 thr, 5 grid barriers.
// Co-residency: __launch_bounds__(256,4) caps VGPR<=128; static LDS 26624B
// -> >=4 blocks/CU * 256 CUs >= 1024 blocks all resident (no deadlock).
__global__ __launch_bounds__(256, 4) void tail_kernel(
    const float* __restrict__ xpart,     // [XSPLIT][L*RPROJ] x_proj partials
    float* __restrict__ dbl,             // [L,RPROJ] f32 out
    short* __restrict__ dbl_bf,          // [L,RPROJ] bf16 out
    const short* __restrict__ dtp_w,     // [E,64] bf16
    const float* __restrict__ dtp_b,     // [E]
    short* __restrict__ dt_bf,           // [L,E]
    const short* __restrict__ xc_bf,     // [L,E]
    const short* __restrict__ xz_bf,     // [L,2E] (z at cols E..)
    const float* __restrict__ A_log,     // [E,16]
    const float* __restrict__ Dp,        // [E]
    float* __restrict__ S,               // [NCHUNK][16][E]
    float* __restrict__ sumdt,           // [NCHUNK][E]
    short* __restrict__ y_bf,            // [L,E]
    const short* __restrict__ out_w,     // [DMODEL,E] bf16
    const float* __restrict__ resid,     // [L,DMODEL]
    float* __restrict__ buf_x,           // [L,DMODEL] out
    unsigned* __restrict__ bar)          // 5 counters (pre-zeroed)
{
    __shared__ alignas(16) char smem[26624];
    const int tid = threadIdx.x;
    const int b = blockIdx.x;
    const int lane = tid & 63;
    const int w = tid >> 6;
    const int wr = w >> 1, wc = w & 1;
    const int lrow = lane & 15;
    const int q = lane >> 4;
    const int srow = tid >> 2;
    const int skch = ((tid & 3) ^ ((srow >> 1) & 3)) * 8;

    // ---- P0: x_proj split-K combine -> dbl f32 + dbl_bf ----
    {
        const int idx = b * 256 + tid;                  // f4 units
        if (idx < (LSEQ * RPROJ) / 4) {
            const int i = idx * 4;
            const int SS = LSEQ * RPROJ;
            float4 v = *(const float4*)(xpart + i);
#pragma unroll
            for (int s = 1; s < XSPLIT; s++) {
                const float4 p = *(const float4*)(xpart + s * SS + i);
                v.x += p.x; v.y += p.y; v.z += p.z; v.w += p.w;
            }
            *(float4*)(dbl + i) = v;
            alignas(8) short hh[4] = {f2bf(v.x), f2bf(v.y), f2bf(v.z), f2bf(v.w)};
            *(unsigned long long*)(dbl_bf + i) = *(const unsigned long long*)hh;
        }
    }
    gridbar(bar + 0);

    // ---- P1: dt_proj GEMM (64x128 tiles, K=64) + softplus+bias -> dt_bf ----
    if (b < 512) {
        short* As = (short*)smem;            // 64*32 shorts = 4KB
        short* Ws = (short*)(smem + 4096);   // 128*32 shorts = 8KB
        const int col0 = (b & 15) * 128;
        const int row0 = (b >> 4) * 64;
        f32x4 acc[2][4];
#pragma unroll
        for (int i = 0; i < 2; i++)
#pragma unroll
            for (int j = 0; j < 4; j++) acc[i][j] = (f32x4)0.f;
#pragma unroll
        for (int kt = 0; kt < 64; kt += 32) {
            __syncthreads();
            {
                const short* gp = dbl_bf + (size_t)(row0 + srow) * RPROJ + kt + skch;
                __builtin_amdgcn_global_load_lds(
                    (const __attribute__((address_space(1))) void*)gp,
                    (__attribute__((address_space(3))) void*)(As + tid * 8), 16, 0, 0);
            }
#pragma unroll
            for (int j = 0; j < 2; j++) {
                const short* gp = dtp_w + (size_t)(col0 + j * 64 + srow) * DTRANK + kt + skch;
                __builtin_amdgcn_global_load_lds(
                    (const __attribute__((address_space(1))) void*)gp,
                    (__attribute__((address_space(3))) void*)(Ws + j * 2048 + tid * 8),
                    16, 0, 0);
            }
            __syncthreads();
            bf16x8 af[2], bfr[4];
#pragma unroll
            for (int i = 0; i < 2; i++) {
                const int R = wr * 32 + i * 16 + lrow;
                af[i] = *(const bf16x8*)&As[R * 32 + ((q ^ ((R >> 1) & 3)) * 8)];
            }
#pragma unroll
            for (int j = 0; j < 4; j++) {
                const int R = wc * 64 + j * 16 + lrow;
                bfr[j] = *(const bf16x8*)&Ws[R * 32 + ((q ^ ((R >> 1) & 3)) * 8)];
            }
#pragma unroll
            for (int i = 0; i < 2; i++)
#pragma unroll
                for (int j = 0; j < 4; j++)
                    acc[i][j] = __builtin_amdgcn_mfma_f32_16x16x32_bf16(
                        af[i], bfr[j], acc[i][j], 0, 0, 0);
        }
        const int rbase = row0 + wr * 32;
        const int cbase = col0 + wc * 64;
#pragma unroll
        for (int i = 0; i < 2; i++)
#pragma unroll
            for (int j = 0; j < 4; j++) {
                const int gcol = cbase + j * 16 + lrow;
#pragma unroll
                for (int r = 0; r < 4; r++) {
                    const int grow = rbase + i * 16 + (lane >> 4) * 4 + r;
                    dt_bf[(size_t)grow * DINNER + gcol] =
                        f2bf(softplusf(acc[i][j][r] + dtp_b[gcol]));
                }
            }
    }
    gridbar(bar + 1);

    // ---- P2: scan pass1 (chunk-local) ----
    const int es = b & 7, c = b >> 3;     // 8 e-slices x 128 chunks
    unsigned short* dtS = (unsigned short*)smem;          // 16x256
    unsigned short* xcS = dtS + 4096;
    unsigned short* zS  = xcS + 4096;
    float* sBC = (float*)(smem + 24576);                  // 16x32
    {
        __syncthreads();   // LDS reuse after P1
        for (int i = tid; i < 512; i += 256) {
            const int t = i >> 5, g = i & 31;
            const size_t col = (size_t)es * 256 + g * 8;
            *(uint4*)(dtS + t * 256 + g * 8) =
                *(const uint4*)(dt_bf + (size_t)(c * 16 + t) * DINNER + col);
            *(uint4*)(xcS + t * 256 + g * 8) =
                *(const uint4*)(xc_bf + (size_t)(c * 16 + t) * DINNER + col);
            *(uint4*)(zS + t * 256 + g * 8) =
                *(const uint4*)(xz_bf + (size_t)(c * 16 + t) * (2 * DINNER) + DINNER + col);
        }
        for (int i = tid; i < 512; i += 256) {
            const int t = i >> 5, j = i & 31;
            sBC[t * 32 + j] = dbl[(size_t)(c * 16 + t) * RPROJ + DTRANK + j];
        }
        __syncthreads();
    }
    const int e = es * 256 + tid;
    float a[DSTATE];
#pragma unroll
    for (int n = 0; n < DSTATE; n++) a[n] = -__expf(A_log[(size_t)e * DSTATE + n]);
    {
        float h[DSTATE];
#pragma unroll
        for (int n = 0; n < DSTATE; n++) h[n] = 0.f;
        float sd = 0.f;
#pragma unroll
        for (int t = 0; t < CHUNK; t++) {
            const float dtv = bf2f((short)dtS[t * 256 + tid]);
            const float du = dtv * bf2f((short)xcS[t * 256 + tid]);
            sd += dtv;
#pragma unroll
            for (int n = 0; n < DSTATE; n++) {
                const float dA = __expf(dtv * a[n]);
                h[n] = dA * h[n] + du * sBC[t * 32 + n];
            }
        }
        sumdt[(size_t)c * DINNER + e] = sd;
#pragma unroll
        for (int n = 0; n < DSTATE; n++)
            S[((size_t)c * DSTATE + n) * DINNER + e] = h[n];
    }
    gridbar(bar + 2);

    // ---- P3: scan pass2 (sequential combine, 128 blocks active) ----
    if (b < 128) {
        const int idx = b * 256 + tid;
        const int e2 = idx & (DINNER - 1);
        const int n2 = idx >> 11;
        const float a2 = -__expf(A_log[(size_t)e2 * DSTATE + n2]);
        const size_t base = (size_t)n2 * DINNER + e2;
        const size_t cstr = (size_t)DSTATE * DINNER;
        float H = 0.f;
        float sc = S[base];
        float sd = sumdt[e2];
        for (int cc = 0; cc < NCHUNK; cc++) {
            float sc_n = 0.f, sd_n = 0.f;
            if (cc + 1 < NCHUNK) {
                sc_n = S[base + (size_t)(cc + 1) * cstr];
                sd_n = sumdt[(size_t)(cc + 1) * DINNER + e2];
            }
            S[base + (size_t)cc * cstr] = H;
            H = __expf(a2 * sd) * H + sc;
            sc = sc_n; sd = sd_n;
        }
    }
    gridbar(bar + 3);

    // ---- P4: scan pass3 (seeded, chunk data still in LDS) -> y_bf ----
    {
        float h[DSTATE];
#pragma unroll
        for (int n = 0; n < DSTATE; n++)
            h[n] = S[((size_t)c * DSTATE + n) * DINNER + e];
        const float dskip = Dp[e];
#pragma unroll
        for (int t = 0; t < CHUNK; t++) {
            const float dtv = bf2f((short)dtS[t * 256 + tid]);
            const float xcv = bf2f((short)xcS[t * 256 + tid]);
            const float du = dtv * xcv;
            float yv = 0.f;
#pragma unroll
            for (int n = 0; n < DSTATE; n++) {
                const float dA = __expf(dtv * a[n]);
                h[n] = dA * h[n] + du * sBC[t * 32 + n];
                yv += h[n] * sBC[t * 32 + 16 + n];
            }
            yv = (yv + xcv * dskip) * siluf(bf2f((short)zS[t * 256 + tid]));
            y_bf[(size_t)(c * 16 + t) * DINNER + e] = f2bf(yv);
        }
    }
    gridbar(bar + 4);

    // ---- P5: out_proj GEMM (64x64 tiles, K=2048, dbuf) + residual ----
    if (b < 512) {
        short* As2 = (short*)smem;            // 2 x 2048 shorts = 8KB
        short* Ws2 = (short*)(smem + 8192);   // 2 x 2048 shorts = 8KB
        const int col0 = (b & 15) * 64;
        const int row0 = (b >> 4) * 64;
        f32x4 acc[2][2];
#pragma unroll
        for (int i = 0; i < 2; i++)
#pragma unroll
            for (int j = 0; j < 2; j++) acc[i][j] = (f32x4)0.f;

        auto stage5 = [&](int p, int kt) {
            const short* gpA = y_bf + (size_t)(row0 + srow) * DINNER + kt + skch;
            __builtin_amdgcn_global_load_lds(
                (const __attribute__((address_space(1))) void*)gpA,
                (__attribute__((address_space(3))) void*)(As2 + p * 2048 + tid * 8),
                16, 0, 0);
            const short* gpW = out_w + (size_t)(col0 + srow) * DINNER + kt + skch;
            __builtin_amdgcn_global_load_lds(
                (const __attribute__((address_space(1))) void*)gpW,
                (__attribute__((address_space(3))) void*)(Ws2 + p * 2048 + tid * 8),
                16, 0, 0);
        };
        __syncthreads();   // LDS reuse after P2/P4
        stage5(0, 0);
        __syncthreads();
        for (int it = 0; it < DINNER / 32; ++it) {
            const int p = it & 1;
            if (it + 1 < DINNER / 32) stage5(p ^ 1, (it + 1) * 32);
            bf16x8 af[2], bfr[2];
#pragma unroll
            for (int i = 0; i < 2; i++) {
                const int R = wr * 32 + i * 16 + lrow;
                af[i] = *(const bf16x8*)&As2[p * 2048 + R * 32 + ((q ^ ((R >> 1) & 3)) * 8)];
            }
#pragma unroll
            for (int j = 0; j < 2; j++) {
                const int R = wc * 32 + j * 16 + lrow;
                bfr[j] = *(const bf16x8*)&Ws2[p * 2048 + R * 32 + ((q ^ ((R >> 1) & 3)) * 8)];
            }
#pragma unroll
            for (int i = 0; i < 2; i++)
#pragma unroll
                for (int j = 0; j < 2; j++)
                    acc[i][j] = __builtin_amdgcn_mfma_f32_16x16x32_bf16(
                        af[i], bfr[j], acc[i][j], 0, 0, 0);
            __syncthreads();
        }
        const int rbase = row0 + wr * 32;
        const int cbase = col0 + wc * 32;
#pragma unroll
        for (int i = 0; i < 2; i++)
#pragma unroll
            for (int j = 0; j < 2; j++) {
                const int gcol = cbase + j * 16 + lrow;
#pragma unroll
                for (int r = 0; r < 4; r++) {
                    const int grow = rbase + i * 16 + (lane >> 4) * 4 + r;
                    buf_x[(size_t)grow * DMODEL + gcol] =
                        acc[i][j][r] + resid[(size_t)grow * DMODEL + gcol];
                }
            }
    }
}

extern "C" void kernel_launch(void* const* d_in, const int* in_sizes, int n_in,
                              void* d_out, int out_size, void* d_ws, size_t ws_size,
                              hipStream_t stream) {
    const float* x_in   = (const float*)d_in[0];
    const float* ln_w   = (const float*)d_in[1];
    const float* ln_b   = (const float*)d_in[2];
    const float* in_w   = (const float*)d_in[3];
    const float* conv_w = (const float*)d_in[4];
    const float* conv_b = (const float*)d_in[5];
    const float* xp_w   = (const float*)d_in[6];
    const float* dtp_w  = (const float*)d_in[7];
    const float* dtp_b  = (const float*)d_in[8];
    const float* A_log  = (const float*)d_in[9];
    const float* D_skip = (const float*)d_in[10];
    const float* out_w  = (const float*)d_in[11];
    const float* nf_w   = (const float*)d_in[12];
    const float* nf_b   = (const float*)d_in[13];
    float* out = (float*)d_out;

    float* w = (float*)d_ws;
    float* buf_x = w; w += (size_t)LSEQ * DMODEL;
    float* dbl   = w; w += (size_t)LSEQ * RPROJ;
    float* xpart = w; w += (size_t)XSPLIT * LSEQ * RPROJ;
    float* Sbuf  = w; w += (size_t)NCHUNK * DSTATE * DINNER;
    float* sumdt = w; w += (size_t)NCHUNK * DINNER;
    unsigned* bar = (unsigned*)w; w += 16;               // 2 layers x 8 counters
    short* h_bf    = (short*)w; w += (size_t)LSEQ * DMODEL / 2;
    short* xz_bf   = (short*)w; w += (size_t)LSEQ * 2 * DINNER / 2;
    short* xc_bf   = (short*)w; w += (size_t)LSEQ * DINNER / 2;
    short* dt_bf   = (short*)w; w += (size_t)LSEQ * DINNER / 2;
    short* y_bf    = (short*)w; w += (size_t)LSEQ * DINNER / 2;
    short* dbl_bf  = (short*)w; w += (size_t)LSEQ * RPROJ / 2 + 1;
    short* in_w_bf  = (short*)w; w += (size_t)2 * (2 * DINNER) * DMODEL / 2;
    short* xp_w_bf  = (short*)w; w += (size_t)2 * RPROJ * DINNER / 2;
    short* dtp_w_bf = (short*)w; w += (size_t)2 * DINNER * DTRANK / 2;
    short* out_w_bf = (short*)w; w += (size_t)2 * DMODEL * DINNER / 2;

    // fused weight conversion + barrier-counter zeroing (one dispatch)
    {
        const int n1 = 2 * (2 * DINNER) * DMODEL;
        const int n2 = 2 * RPROJ * DINNER;
        const int n3 = 2 * DMODEL * DINNER;
        const int n4 = 2 * DINNER * DTRANK;
        const int total = n1 + n2 + n3 + n4;
        cvt_weights<<<dim3(total / (256 * 8)), dim3(256), 0, stream>>>(
            in_w, in_w_bf, n1, xp_w, xp_w_bf, n2,
            out_w, out_w_bf, n3, dtp_w, dtp_w_bf, n4, bar);
    }

    for (int layer = 0; layer < 2; layer++) {
        const float* resid_src = (layer == 0) ? x_in : buf_x;
        // 1. LayerNorm -> bf16
        ln_kernel<<<dim3(LSEQ), dim3(256), 0, stream>>>(
            resid_src, ln_w + layer * DMODEL, ln_b + layer * DMODEL,
            nullptr, h_bf);
        // 2. in_proj (MFMA 64x128 dbuf, bf16 out)
        gemm_mfma<2, 4, 3><<<dim3((2 * DINNER) / 128, LSEQ / 64), dim3(256), 0, stream>>>(
            h_bf, DMODEL, in_w_bf + (size_t)layer * 2 * DINNER * DMODEL, DMODEL,
            nullptr, xz_bf, 2 * DINNER, LSEQ, 2 * DINNER, DMODEL, 0);
        // 3. conv + silu -> bf16
        conv_silu_kernel<<<dim3((LSEQ * DINNER / 8) / 256), dim3(256), 0, stream>>>(
            xz_bf, conv_w + (size_t)layer * DINNER * DCONV, conv_b + layer * DINNER,
            xc_bf);
        // 4. x_proj (MFMA 64x64 dbuf, split-K=4 -> partials)
        gemm_mfma<2, 2, 0><<<dim3(2, LSEQ / 64, XSPLIT), dim3(256), 0, stream>>>(
            xc_bf, DINNER, xp_w_bf + (size_t)layer * RPROJ * DINNER, DINNER,
            xpart, nullptr, RPROJ, LSEQ, RPROJ, DINNER / XSPLIT,
            (size_t)LSEQ * RPROJ);
        // 5. fused tail: combine + dt_proj + scan + out_proj (5 grid barriers)
        tail_kernel<<<dim3(TGRID), dim3(256), 0, stream>>>(
            xpart, dbl, dbl_bf,
            dtp_w_bf + (size_t)layer * DINNER * DTRANK, dtp_b + layer * DINNER,
            dt_bf, xc_bf, xz_bf,
            A_log + (size_t)layer * DINNER * DSTATE, D_skip + layer * DINNER,
            Sbuf, sumdt, y_bf,
            out_w_bf + (size_t)layer * DMODEL * DINNER, resid_src, buf_x,
            bar + layer * 8);
    }
    // final LayerNorm -> d_out (f32)
    ln_kernel<<<dim3(LSEQ), dim3(256), 0, stream>>>(buf_x, nf_w, nf_b, out, nullptr);
}

// Round 10
// 458.850 us; speedup vs baseline: 6.7190x; 6.7190x over previous
//
#include <hip/hip_runtime.h>
#include <hip/hip_bf16.h>
#include <math.h>

// Problem constants
#define LSEQ 2048
#define DMODEL 1024
#define DINNER 2048
#define DSTATE 16
#define DCONV 4
#define DTRANK 64
#define RPROJ 96   // DTRANK + 2*DSTATE

// Chunked-scan decomposition
#define CHUNK 16
#define NCHUNK (LSEQ / CHUNK)   // 128

#define XSPLIT 4                // split-K factor for x_proj

typedef __attribute__((ext_vector_type(8))) short bf16x8;
typedef __attribute__((ext_vector_type(4))) float f32x4;

__device__ __forceinline__ float softplusf(float x) {
    return (x > 20.f) ? x : log1pf(__expf(x));
}
__device__ __forceinline__ float siluf(float x) {
    return x / (1.f + __expf(-x));
}
// f32 -> bf16 RTNE
__device__ __forceinline__ short f2bf(float f) {
    union { float f; unsigned u; } v; v.f = f;
    unsigned r = v.u + 0x7FFFu + ((v.u >> 16) & 1u);
    return (short)(r >> 16);
}
// bf16 -> f32
__device__ __forceinline__ float bf2f(short h) {
    union { unsigned u; float f; } v;
    v.u = ((unsigned)(unsigned short)h) << 16;
    return v.f;
}

__device__ __forceinline__ void cvt8(const float* __restrict__ s,
                                     short* __restrict__ d, int i) {
    const float4 a = *(const float4*)(s + i);
    const float4 b = *(const float4*)(s + i + 4);
    alignas(16) short h[8];
    h[0] = f2bf(a.x); h[1] = f2bf(a.y); h[2] = f2bf(a.z); h[3] = f2bf(a.w);
    h[4] = f2bf(b.x); h[5] = f2bf(b.y); h[6] = f2bf(b.z); h[7] = f2bf(b.w);
    *(uint4*)(d + i) = *(const uint4*)h;
}

// ---------------- fused f32 -> bf16 convert of all 4 weight tensors -------
__global__ __launch_bounds__(256) void cvt_weights(
    const float* __restrict__ s0, short* __restrict__ d0, int n0,
    const float* __restrict__ s1, short* __restrict__ d1, int n1,
    const float* __restrict__ s2, short* __restrict__ d2, int n2,
    const float* __restrict__ s3, short* __restrict__ d3, int n3)
{
    int i = (blockIdx.x * 256 + threadIdx.x) * 8;
    if (i < n0) { cvt8(s0, d0, i); return; }
    i -= n0;
    if (i < n1) { cvt8(s1, d1, i); return; }
    i -= n1;
    if (i < n2) { cvt8(s2, d2, i); return; }
    i -= n2;
    if (i < n3) { cvt8(s3, d3, i); return; }
}

// ---------------- LayerNorm: one block per row; f32 or bf16 out ----------
__global__ __launch_bounds__(256) void ln_kernel(
    const float* __restrict__ x, const float* __restrict__ w,
    const float* __restrict__ b, float* __restrict__ outf,
    short* __restrict__ outb)
{
    __shared__ float s1[256], s2[256];
    const int row = blockIdx.x;
    const int tid = threadIdx.x;
    const float* xr = x + (size_t)row * DMODEL;
    float v[4];
    float s = 0.f, sq = 0.f;
#pragma unroll
    for (int k = 0; k < 4; k++) {
        v[k] = xr[k * 256 + tid];
        s += v[k];
        sq += v[k] * v[k];
    }
    s1[tid] = s; s2[tid] = sq;
    __syncthreads();
    for (int off = 128; off > 0; off >>= 1) {
        if (tid < off) { s1[tid] += s1[tid + off]; s2[tid] += s2[tid + off]; }
        __syncthreads();
    }
    const float mu = s1[0] * (1.f / DMODEL);
    const float var = s2[0] * (1.f / DMODEL) - mu * mu;
    const float rstd = rsqrtf(var + 1e-5f);
#pragma unroll
    for (int k = 0; k < 4; k++) {
        const int i = k * 256 + tid;
        const float o = (v[k] - mu) * rstd * w[i] + b[i];
        if (outf) outf[(size_t)row * DMODEL + i] = o;
        if (outb) outb[(size_t)row * DMODEL + i] = f2bf(o);
    }
}

// ------ bf16 MFMA NT GEMM, (32*MI) x (32*NJ) tile, XOR-swizzled LDS ------
// C[M,N] = A[M,K] * W[N,K]^T; K per z-slice (blockIdx.z offsets A/W by z*K).
// Single-buffered (m97-style; R8 showed dbuf neutral). 2x2 waves.
// XOR swizzle: row r chunk c at phys chunk c ^ ((r>>1)&3) -> 2-way bank
// aliasing (free) for quarter-wave ds_read_b128.
// MODE 2: f32 (. + resid)   MODE 3: bf16 store   MODE 6: atomicAdd f32
template<int MI, int NJ, int MODE>
__global__ __launch_bounds__(256) void gemm_mfma(
    const short* __restrict__ A, int lda,   // [M,lda] bf16
    const short* __restrict__ W, int ldw,   // [N,ldw] bf16
    float* __restrict__ Cf, short* __restrict__ Cb, int ldc,
    int M, int N, int K,
    const float* __restrict__ resid)
{
    constexpr int BM = 32 * MI;
    constexpr int BN = 32 * NJ;
    constexpr int AISS = BM / 64;
    constexpr int WISS = BN / 64;
    __shared__ alignas(16) short As[BM * 32];
    __shared__ alignas(16) short Ws[BN * 32];

    const int tid = threadIdx.x;
    const int lane = tid & 63;
    const int w = tid >> 6;
    const int wr = w >> 1, wc = w & 1;
    const int row0 = blockIdx.y * BM;
    const int col0 = blockIdx.x * BN;
    const int kbeg = blockIdx.z * K;

    const int srow = tid >> 2;
    const int skch = ((tid & 3) ^ ((srow >> 1) & 3)) * 8;   // swizzled k chunk

    f32x4 acc[MI][NJ];
#pragma unroll
    for (int i = 0; i < MI; i++)
#pragma unroll
        for (int j = 0; j < NJ; j++) acc[i][j] = (f32x4)0.f;

    const int lrow = lane & 15;
    const int q = lane >> 4;

    for (int kt = kbeg; kt < kbeg + K; kt += 32) {
        __syncthreads();
#pragma unroll
        for (int j = 0; j < AISS; j++) {
            const short* gp = A + (size_t)(row0 + j * 64 + srow) * lda + kt + skch;
            __builtin_amdgcn_global_load_lds(
                (const __attribute__((address_space(1))) void*)gp,
                (__attribute__((address_space(3))) void*)(&As[j * 2048 + tid * 8]),
                16, 0, 0);
        }
#pragma unroll
        for (int j = 0; j < WISS; j++) {
            const int wrow = col0 + j * 64 + srow;
            if (wrow < N) {
                const short* gp = W + (size_t)wrow * ldw + kt + skch;
                __builtin_amdgcn_global_load_lds(
                    (const __attribute__((address_space(1))) void*)gp,
                    (__attribute__((address_space(3))) void*)(&Ws[j * 2048 + tid * 8]),
                    16, 0, 0);
            }
        }
        __syncthreads();

        bf16x8 af[MI], bfr[NJ];
#pragma unroll
        for (int i = 0; i < MI; i++) {
            const int R = wr * (16 * MI) + i * 16 + lrow;
            af[i] = *(const bf16x8*)&As[R * 32 + ((q ^ ((R >> 1) & 3)) * 8)];
        }
#pragma unroll
        for (int j = 0; j < NJ; j++) {
            const int R = wc * (16 * NJ) + j * 16 + lrow;
            bfr[j] = *(const bf16x8*)&Ws[R * 32 + ((q ^ ((R >> 1) & 3)) * 8)];
        }
#pragma unroll
        for (int i = 0; i < MI; i++)
#pragma unroll
            for (int j = 0; j < NJ; j++)
                acc[i][j] = __builtin_amdgcn_mfma_f32_16x16x32_bf16(
                    af[i], bfr[j], acc[i][j], 0, 0, 0);
    }

    // epilogue: C/D layout col=lane&15, row=(lane>>4)*4+reg
    const int rbase = row0 + wr * (16 * MI);
    const int cbase = col0 + wc * (16 * NJ);
#pragma unroll
    for (int i = 0; i < MI; i++) {
#pragma unroll
        for (int j = 0; j < NJ; j++) {
            const int gcol = cbase + j * 16 + lrow;
            if (gcol < N) {
#pragma unroll
                for (int r = 0; r < 4; r++) {
                    const int grow = rbase + i * 16 + (lane >> 4) * 4 + r;
                    float v = acc[i][j][r];
                    if (MODE == 2) {
                        Cf[(size_t)grow * ldc + gcol] =
                            v + resid[(size_t)grow * ldc + gcol];
                    } else if (MODE == 3) {
                        Cb[(size_t)grow * ldc + gcol] = f2bf(v);
                    } else {  // MODE 6: split-K accumulate
                        atomicAdd(&Cf[(size_t)grow * ldc + gcol], v);
                    }
                }
            }
        }
    }
}

// ---------- dt_proj: 64x128 tile, K=64; A staged from f32 dbl ------------
// A tile converted f32->bf16 in registers, ds_write (swizzled); W via
// global_load_lds. Epilogue: softplus(.+bias) -> bf16.
__global__ __launch_bounds__(256) void dtproj_kernel(
    const float* __restrict__ dbl,      // [L,RPROJ] f32 (cols 0..63 used)
    const short* __restrict__ dtp_w,    // [DINNER,64] bf16
    const float* __restrict__ dtp_b,    // [DINNER]
    short* __restrict__ dt_bf)          // [L,DINNER]
{
    __shared__ alignas(16) short As[64 * 32];
    __shared__ alignas(16) short Ws[128 * 32];
    const int tid = threadIdx.x;
    const int lane = tid & 63;
    const int w = tid >> 6;
    const int wr = w >> 1, wc = w & 1;
    const int row0 = blockIdx.y * 64;
    const int col0 = blockIdx.x * 128;
    const int srow = tid >> 2;
    const int skch = ((tid & 3) ^ ((srow >> 1) & 3)) * 8;
    const int lrow = lane & 15;
    const int q = lane >> 4;

    f32x4 acc[2][4];
#pragma unroll
    for (int i = 0; i < 2; i++)
#pragma unroll
        for (int j = 0; j < 4; j++) acc[i][j] = (f32x4)0.f;

#pragma unroll
    for (int kt = 0; kt < 64; kt += 32) {
        __syncthreads();
        // A: load f32, convert, ds_write (same swizzled slot as async path)
        {
            const float* gp = dbl + (size_t)(row0 + srow) * RPROJ + kt + skch;
            const float4 a = *(const float4*)gp;
            const float4 b = *(const float4*)(gp + 4);
            alignas(16) short h[8];
            h[0] = f2bf(a.x); h[1] = f2bf(a.y); h[2] = f2bf(a.z); h[3] = f2bf(a.w);
            h[4] = f2bf(b.x); h[5] = f2bf(b.y); h[6] = f2bf(b.z); h[7] = f2bf(b.w);
            *(uint4*)(As + tid * 8) = *(const uint4*)h;
        }
        // W via async LDS copy
#pragma unroll
        for (int j = 0; j < 2; j++) {
            const short* gp = dtp_w + (size_t)(col0 + j * 64 + srow) * DTRANK + kt + skch;
            __builtin_amdgcn_global_load_lds(
                (const __attribute__((address_space(1))) void*)gp,
                (__attribute__((address_space(3))) void*)(&Ws[j * 2048 + tid * 8]),
                16, 0, 0);
        }
        __syncthreads();

        bf16x8 af[2], bfr[4];
#pragma unroll
        for (int i = 0; i < 2; i++) {
            const int R = wr * 32 + i * 16 + lrow;
            af[i] = *(const bf16x8*)&As[R * 32 + ((q ^ ((R >> 1) & 3)) * 8)];
        }
#pragma unroll
        for (int j = 0; j < 4; j++) {
            const int R = wc * 64 + j * 16 + lrow;
            bfr[j] = *(const bf16x8*)&Ws[R * 32 + ((q ^ ((R >> 1) & 3)) * 8)];
        }
#pragma unroll
        for (int i = 0; i < 2; i++)
#pragma unroll
            for (int j = 0; j < 4; j++)
                acc[i][j] = __builtin_amdgcn_mfma_f32_16x16x32_bf16(
                    af[i], bfr[j], acc[i][j], 0, 0, 0);
    }

    const int rbase = row0 + wr * 32;
    const int cbase = col0 + wc * 64;
#pragma unroll
    for (int i = 0; i < 2; i++)
#pragma unroll
        for (int j = 0; j < 4; j++) {
            const int gcol = cbase + j * 16 + lrow;
#pragma unroll
            for (int r = 0; r < 4; r++) {
                const int grow = rbase + i * 16 + (lane >> 4) * 4 + r;
                dt_bf[(size_t)grow * DINNER + gcol] =
                    f2bf(softplusf(acc[i][j][r] + dtp_b[gcol]));
            }
        }
}

// ---------------- Causal depthwise conv (k=4) + bias + silu --------------
// Also zero-fills dbl (d_ws is poisoned) so x_proj can atomicAdd into it.
__global__ __launch_bounds__(256) void conv_silu_kernel(
    const short* __restrict__ xzb, const float* __restrict__ cw,
    const float* __restrict__ cb, short* __restrict__ xcb,
    float* __restrict__ dbl_zero)
{
    const int g = blockIdx.x * 256 + threadIdx.x;   // over L * DINNER/8
    if (g < (LSEQ * RPROJ) / 4)
        *(float4*)(dbl_zero + g * 4) = make_float4(0.f, 0.f, 0.f, 0.f);
    const int t = g >> 8;
    const int c0 = (g & 255) * 8;
    float acc[8];
#pragma unroll
    for (int j = 0; j < 8; j++) acc[j] = cb[c0 + j];
#pragma unroll
    for (int k = 0; k < DCONV; k++) {
        const int tt = t - (DCONV - 1) + k;
        if (tt >= 0) {
            const bf16x8 v = *(const bf16x8*)(xzb + (size_t)tt * (2 * DINNER) + c0);
#pragma unroll
            for (int j = 0; j < 8; j++)
                acc[j] += bf2f(v[j]) * cw[(c0 + j) * DCONV + k];
        }
    }
    alignas(16) short h[8];
#pragma unroll
    for (int j = 0; j < 8; j++) h[j] = f2bf(siluf(acc[j]));
    *(uint4*)(xcb + (size_t)t * DINNER + c0) = *(const uint4*)h;
}

// ============ Chunked selective scan ============
__global__ __launch_bounds__(256) void scan_pass1(
    const short* __restrict__ dtb,   // [L, DINNER] bf16
    const short* __restrict__ xcb,   // [L, DINNER] bf16
    const float* __restrict__ dbl,   // [L, RPROJ] f32
    const float* __restrict__ A_log,
    float* __restrict__ S,           // [NCHUNK][DSTATE][DINNER]
    float* __restrict__ sumdt)       // [NCHUNK][DINNER]
{
    const int e = blockIdx.x * 256 + threadIdx.x;
    const int c = blockIdx.y;
    float a[DSTATE];
#pragma unroll
    for (int n = 0; n < DSTATE; n++) a[n] = -__expf(A_log[(size_t)e * DSTATE + n]);
    float h[DSTATE];
#pragma unroll
    for (int n = 0; n < DSTATE; n++) h[n] = 0.f;
    float sd = 0.f;

    __shared__ float sBC[CHUNK][32];
    for (int i = threadIdx.x; i < CHUNK * 32; i += 256) {
        const int tl = i >> 5, j = i & 31;
        sBC[tl][j] = dbl[(size_t)(c * CHUNK + tl) * RPROJ + DTRANK + j];
    }
    __syncthreads();

    const size_t rb = (size_t)c * CHUNK * DINNER + e;
    short dt_c = dtb[rb], xc_c = xcb[rb];
#pragma unroll
    for (int tl = 0; tl < CHUNK; tl++) {
        short dt_n = 0, xc_n = 0;
        if (tl + 1 < CHUNK) {
            dt_n = dtb[rb + (size_t)(tl + 1) * DINNER];
            xc_n = xcb[rb + (size_t)(tl + 1) * DINNER];
        }
        const float dtv = bf2f(dt_c);
        const float du = dtv * bf2f(xc_c);
        sd += dtv;
#pragma unroll
        for (int n = 0; n < DSTATE; n++) {
            const float dA = __expf(dtv * a[n]);
            h[n] = dA * h[n] + du * sBC[tl][n];
        }
        dt_c = dt_n; xc_c = xc_n;
    }
    sumdt[(size_t)c * DINNER + e] = sd;
#pragma unroll
    for (int n = 0; n < DSTATE; n++)
        S[((size_t)c * DSTATE + n) * DINNER + e] = h[n];
}

__global__ __launch_bounds__(256) void scan_pass2(
    const float* __restrict__ A_log,
    const float* __restrict__ sumdt,
    float* __restrict__ S)
{
    const int idx = blockIdx.x * 256 + threadIdx.x;
    const int e = idx & (DINNER - 1);
    const int n = idx >> 11;
    const float a = -__expf(A_log[(size_t)e * DSTATE + n]);
    const size_t base = (size_t)n * DINNER + e;
    const size_t cstr = (size_t)DSTATE * DINNER;
    float H = 0.f;
    float sc = S[base];
    float sd = sumdt[e];
    for (int c = 0; c < NCHUNK; c++) {
        float sc_n = 0.f, sd_n = 0.f;
        if (c + 1 < NCHUNK) {
            sc_n = S[base + (size_t)(c + 1) * cstr];
            sd_n = sumdt[(size_t)(c + 1) * DINNER + e];
        }
        S[base + (size_t)c * cstr] = H;
        H = __expf(a * sd) * H + sc;
        sc = sc_n; sd = sd_n;
    }
}

__global__ __launch_bounds__(256) void scan_pass3(
    const short* __restrict__ dtb,
    const short* __restrict__ xcb,
    const float* __restrict__ dbl,
    const short* __restrict__ xzb,   // z at cols DINNER.. (bf16)
    const float* __restrict__ A_log,
    const float* __restrict__ Dp,
    const float* __restrict__ S,
    short* __restrict__ yb)
{
    const int e = blockIdx.x * 256 + threadIdx.x;
    const int c = blockIdx.y;
    float a[DSTATE];
#pragma unroll
    for (int n = 0; n < DSTATE; n++) a[n] = -__expf(A_log[(size_t)e * DSTATE + n]);
    float h[DSTATE];
#pragma unroll
    for (int n = 0; n < DSTATE; n++)
        h[n] = S[((size_t)c * DSTATE + n) * DINNER + e];
    const float dskip = Dp[e];

    __shared__ float sBC[CHUNK][32];
    for (int i = threadIdx.x; i < CHUNK * 32; i += 256) {
        const int tl = i >> 5, j = i & 31;
        sBC[tl][j] = dbl[(size_t)(c * CHUNK + tl) * RPROJ + DTRANK + j];
    }
    __syncthreads();

    const size_t rb = (size_t)c * CHUNK * DINNER + e;
    const size_t zb = (size_t)c * CHUNK * (2 * DINNER) + DINNER + e;
    short dt_c = dtb[rb], xc_c = xcb[rb], z_c = xzb[zb];
#pragma unroll
    for (int tl = 0; tl < CHUNK; tl++) {
        short dt_n = 0, xc_n = 0, z_n = 0;
        if (tl + 1 < CHUNK) {
            dt_n = dtb[rb + (size_t)(tl + 1) * DINNER];
            xc_n = xcb[rb + (size_t)(tl + 1) * DINNER];
            z_n = xzb[zb + (size_t)(tl + 1) * (2 * DINNER)];
        }
        const float dtv = bf2f(dt_c);
        const float xcv = bf2f(xc_c);
        const float du = dtv * xcv;
        float yv = 0.f;
#pragma unroll
        for (int n = 0; n < DSTATE; n++) {
            const float dA = __expf(dtv * a[n]);
            h[n] = dA * h[n] + du * sBC[tl][n];
            yv += h[n] * sBC[tl][16 + n];
        }
        yv = (yv + xcv * dskip) * siluf(bf2f(z_c));
        yb[rb + (size_t)tl * DINNER] = f2bf(yv);
        dt_c = dt_n; xc_c = xc_n; z_c = z_n;
    }
}

extern "C" void kernel_launch(void* const* d_in, const int* in_sizes, int n_in,
                              void* d_out, int out_size, void* d_ws, size_t ws_size,
                              hipStream_t stream) {
    const float* x_in   = (const float*)d_in[0];
    const float* ln_w   = (const float*)d_in[1];
    const float* ln_b   = (const float*)d_in[2];
    const float* in_w   = (const float*)d_in[3];
    const float* conv_w = (const float*)d_in[4];
    const float* conv_b = (const float*)d_in[5];
    const float* xp_w   = (const float*)d_in[6];
    const float* dtp_w  = (const float*)d_in[7];
    const float* dtp_b  = (const float*)d_in[8];
    const float* A_log  = (const float*)d_in[9];
    const float* D_skip = (const float*)d_in[10];
    const float* out_w  = (const float*)d_in[11];
    const float* nf_w   = (const float*)d_in[12];
    const float* nf_b   = (const float*)d_in[13];
    float* out = (float*)d_out;

    float* w = (float*)d_ws;
    float* buf_x = w; w += (size_t)LSEQ * DMODEL;              // residual stream (f32)
    float* dbl   = w; w += (size_t)LSEQ * RPROJ;               // x_proj out (f32)
    float* Sbuf  = w; w += (size_t)NCHUNK * DSTATE * DINNER;   // chunk summaries
    float* sumdt = w; w += (size_t)NCHUNK * DINNER;
    // bf16 buffers (sized in float units, 2 shorts per float)
    short* h_bf    = (short*)w; w += (size_t)LSEQ * DMODEL / 2;
    short* xz_bf   = (short*)w; w += (size_t)LSEQ * 2 * DINNER / 2;
    short* xc_bf   = (short*)w; w += (size_t)LSEQ * DINNER / 2;
    short* dt_bf   = (short*)w; w += (size_t)LSEQ * DINNER / 2;
    short* y_bf    = (short*)w; w += (size_t)LSEQ * DINNER / 2;
    short* in_w_bf  = (short*)w; w += (size_t)2 * (2 * DINNER) * DMODEL / 2;
    short* xp_w_bf  = (short*)w; w += (size_t)2 * RPROJ * DINNER / 2;
    short* dtp_w_bf = (short*)w; w += (size_t)2 * DINNER * DTRANK / 2;
    short* out_w_bf = (short*)w; w += (size_t)2 * DMODEL * DINNER / 2;

    // fused weight conversion (all layers, all 4 tensors, one dispatch)
    {
        const int n1 = 2 * (2 * DINNER) * DMODEL;   // 8388608
        const int n2 = 2 * RPROJ * DINNER;          // 393216
        const int n3 = 2 * DMODEL * DINNER;         // 4194304
        const int n4 = 2 * DINNER * DTRANK;         // 262144
        const int total = n1 + n2 + n3 + n4;        // 13238272
        cvt_weights<<<dim3(total / (256 * 8)), dim3(256), 0, stream>>>(
            in_w, in_w_bf, n1, xp_w, xp_w_bf, n2,
            out_w, out_w_bf, n3, dtp_w, dtp_w_bf, n4);
    }

    for (int layer = 0; layer < 2; layer++) {
        const float* resid_src = (layer == 0) ? x_in : buf_x;
        // 1. LayerNorm -> bf16
        ln_kernel<<<dim3(LSEQ), dim3(256), 0, stream>>>(
            resid_src, ln_w + layer * DMODEL, ln_b + layer * DMODEL,
            nullptr, h_bf);
        // 2. in_proj (MFMA 128x128, bf16 out): xz_bf[L,4096] = h * in_w^T
        gemm_mfma<4, 4, 3><<<dim3((2 * DINNER) / 128, LSEQ / 128), dim3(256), 0, stream>>>(
            h_bf, DMODEL, in_w_bf + (size_t)layer * 2 * DINNER * DMODEL, DMODEL,
            nullptr, xz_bf, 2 * DINNER, LSEQ, 2 * DINNER, DMODEL, nullptr);
        // 3. conv + silu -> bf16 (also zero-fills dbl for the atomic split-K)
        conv_silu_kernel<<<dim3((LSEQ * DINNER / 8) / 256), dim3(256), 0, stream>>>(
            xz_bf, conv_w + (size_t)layer * DINNER * DCONV, conv_b + layer * DINNER,
            xc_bf, dbl);
        // 4. x_proj (MFMA 64x64, split-K=4, atomicAdd into dbl)
        gemm_mfma<2, 2, 6><<<dim3(2, LSEQ / 64, XSPLIT), dim3(256), 0, stream>>>(
            xc_bf, DINNER, xp_w_bf + (size_t)layer * RPROJ * DINNER, DINNER,
            dbl, nullptr, RPROJ, LSEQ, RPROJ, DINNER / XSPLIT, nullptr);
        // 5. dt_proj (64x128, K=64, A from f32 dbl, softplus+bias -> bf16)
        dtproj_kernel<<<dim3(DINNER / 128, LSEQ / 64), dim3(256), 0, stream>>>(
            dbl, dtp_w_bf + (size_t)layer * DINNER * DTRANK,
            dtp_b + layer * DINNER, dt_bf);
        // 6. chunked selective scan (+ skip + z-gate) -> y_bf
        const float* Al = A_log + (size_t)layer * DINNER * DSTATE;
        scan_pass1<<<dim3(DINNER / 256, NCHUNK), dim3(256), 0, stream>>>(
            dt_bf, xc_bf, dbl, Al, Sbuf, sumdt);
        scan_pass2<<<dim3((DINNER * DSTATE) / 256), dim3(256), 0, stream>>>(
            Al, sumdt, Sbuf);
        scan_pass3<<<dim3(DINNER / 256, NCHUNK), dim3(256), 0, stream>>>(
            dt_bf, xc_bf, dbl, xz_bf, Al, D_skip + layer * DINNER, Sbuf, y_bf);
        // 7. out_proj (MFMA 64x64) + residual -> buf_x f32
        gemm_mfma<2, 2, 2><<<dim3(DMODEL / 64, LSEQ / 64), dim3(256), 0, stream>>>(
            y_bf, DINNER, out_w_bf + (size_t)layer * DMODEL * DINNER, DINNER,
            buf_x, nullptr, DMODEL, LSEQ, DMODEL, DINNER, resid_src);
    }
    // final LayerNorm -> d_out (f32)
    ln_kernel<<<dim3(LSEQ), dim3(256), 0, stream>>>(buf_x, nf_w, nf_b, out, nullptr);
}